// Round 2
// baseline (446.791 us; speedup 1.0000x reference)
//
#include <hip/hip_runtime.h>
#include <stdint.h>

#define N 8192
#define D 256          // elements per row == bytes per fp8 row
#define INV_T 20.0f
#define LOG2E 1.44269504088896340736f
#define BM 128
#define BN 128
#define NCG 8          // column groups (grid.x) -> XCD id
#define CPG 8          // col-tiles per group; NCG*CPG*BN == N

typedef __attribute__((ext_vector_type(16))) float f32x16;
typedef __attribute__((ext_vector_type(4))) int i32x4;
typedef __attribute__((ext_vector_type(8))) int i32x8;

typedef __attribute__((address_space(3))) uint32_t lds_u32;
typedef __attribute__((address_space(1))) const uint32_t gbl_u32;

// Kernel 1: per-row fp32 normalize -> fp8 e4m3 copies (HW cvt, OCP on gfx950);
// c[i] = (e_i . p_i)/T exact fp32.
__global__ __launch_bounds__(256) void normalize_kernel(
    const float* __restrict__ e, const float* __restrict__ p, const float* __restrict__ n,
    uint32_t* __restrict__ eb, uint32_t* __restrict__ pb, uint32_t* __restrict__ nb,
    float* __restrict__ cbuf) {
  const int tid = threadIdx.x;
  const int wave = tid >> 6, lane = tid & 63;
  const int row = blockIdx.x * 4 + wave;          // one wave per row

  const float4 ev = ((const float4*)(e + (size_t)row * D))[lane];
  const float4 pv = ((const float4*)(p + (size_t)row * D))[lane];
  const float4 nv = ((const float4*)(n + (size_t)row * D))[lane];

  float sse = ev.x*ev.x + ev.y*ev.y + ev.z*ev.z + ev.w*ev.w;
  float ssp = pv.x*pv.x + pv.y*pv.y + pv.z*pv.z + pv.w*pv.w;
  float ssn = nv.x*nv.x + nv.y*nv.y + nv.z*nv.z + nv.w*nv.w;
  float dep = ev.x*pv.x + ev.y*pv.y + ev.z*pv.z + ev.w*pv.w;
#pragma unroll
  for (int m = 1; m < 64; m <<= 1) {
    sse += __shfl_xor(sse, m);
    ssp += __shfl_xor(ssp, m);
    ssn += __shfl_xor(ssn, m);
    dep += __shfl_xor(dep, m);
  }
  const float se = 1.0f / fmaxf(sqrtf(sse), 1e-8f);
  const float sp = 1.0f / fmaxf(sqrtf(ssp), 1e-8f);
  const float sn = 1.0f / fmaxf(sqrtf(ssn), 1e-8f);

  int ue = __builtin_amdgcn_cvt_pk_fp8_f32(ev.x*se, ev.y*se, 0, false);
  ue     = __builtin_amdgcn_cvt_pk_fp8_f32(ev.z*se, ev.w*se, ue, true);
  int up = __builtin_amdgcn_cvt_pk_fp8_f32(pv.x*sp, pv.y*sp, 0, false);
  up     = __builtin_amdgcn_cvt_pk_fp8_f32(pv.z*sp, pv.w*sp, up, true);
  int un = __builtin_amdgcn_cvt_pk_fp8_f32(nv.x*sn, nv.y*sn, 0, false);
  un     = __builtin_amdgcn_cvt_pk_fp8_f32(nv.z*sn, nv.w*sn, un, true);
  eb[row * 64 + lane] = (uint32_t)ue;             // 64 uints = 256 fp8 bytes per row
  pb[row * 64 + lane] = (uint32_t)up;
  nb[row * 64 + lane] = (uint32_t)un;

  if (lane == 0) cbuf[row] = dep * se * sp * INV_T;
}

// Kernel 2: persistent row-tile GEMM with fused exp row-sums.
// Each block owns rows [rowTile, rowTile+128) and walks 8 col-tiles of 128:
//  - A staged ONCE (full K=256, 32 KB), A-fragments then held in REGISTERS
//    (64 VGPRs) for all 8 col-tiles.
//  - B double-buffered (2 x 32 KB full-K tiles) with counted vmcnt: raw
//    s_barrier + "s_waitcnt vmcnt(8)" keeps exactly one B-tile in flight; never
//    drained to 0 in the loop (T3/T4 — __syncthreads would force vmcnt(0)).
//  - LDS layout (proven round 1, 0 bank conflicts): 16B-group gg of row r at
//    slot gg ^ (r & 15) within the 256B row -> only 2-way aliasing (free).
//    Applied by pre-permuting the global SOURCE (gload_lds dest stays linear).
//  - MX-scaled MFMA 32x32x64_f8f6f4 (fmt 0 = e4m3) with unit scales: exact
//    same numerics as non-scaled fp8 at 2x rate (verified round 1, absmax 0).
//  - exp row-sums accumulate in registers across col-tiles; single cross-lane
//    reduce per block. Staging of B(t+2) is issued BEFORE the exp VALU so the
//    L2/L3 latency hides under it (T14).
// Grid (cg, row, z): XCD = linear%8 = cg -> each XCD's 32 CUs share one 512 KB
// B working set (L2-resident).  97.5 KB LDS -> 1 block/CU, reg budget 512/wave.
__global__ __launch_bounds__(256, 1) void simexp_kernel(
    const uint8_t* __restrict__ eb, const uint8_t* __restrict__ pb,
    const uint8_t* __restrict__ nb, const float* __restrict__ cbuf,
    float* __restrict__ part) {
  __shared__ uint8_t As[BM * D];      // 32 KB
  __shared__ uint8_t Bs[2][BN * D];   // 64 KB
  __shared__ float cs[BM];            // 512 B
  __shared__ float sm[BM][2];         // 1 KB

  const int z = blockIdx.z;
  const uint8_t* __restrict__ A = z ? pb : eb;
  const uint8_t* __restrict__ B = z ? eb : nb;

  const int tid = threadIdx.x;
  const int wave = tid >> 6, lane = tid & 63;
  const int lane31 = lane & 31, half = lane >> 5;
  const int cg = blockIdx.x;
  const int rowTile = blockIdx.y * BM;
  const int wr = wave >> 1, wc = wave & 1;        // wave -> 64x64 sub-tile

  // cbuf load issued FIRST: in-order vmem retirement keeps the gl_lds vmcnt
  // arithmetic below exact for all waves (this retires before A).
  float cvload = 0.0f;
  if (tid < BM) cvload = cbuf[rowTile + tid] * LOG2E;

  // ---- stage A (full K), then B0, B1: 8 gl_lds each per thread ----
#pragma unroll
  for (int i = 0; i < 8; ++i) {
    const int c = i * 256 + tid, r = c >> 4, sl = c & 15;
    const int gg = sl ^ (r & 15);
    __builtin_amdgcn_global_load_lds(
        (gbl_u32*)(A + (size_t)(rowTile + r) * D + gg * 16),
        (lds_u32*)&As[c * 16], 16, 0, 0);
  }
#pragma unroll
  for (int t = 0; t < 2; ++t) {
    const int colTile = (cg * CPG + t) * BN;
#pragma unroll
    for (int i = 0; i < 8; ++i) {
      const int c = i * 256 + tid, r = c >> 4, sl = c & 15;
      const int gg = sl ^ (r & 15);
      __builtin_amdgcn_global_load_lds(
          (gbl_u32*)(B + (size_t)(colTile + r) * D + gg * 16),
          (lds_u32*)&Bs[t][c * 16], 16, 0, 0);
    }
  }
  if (tid < BM) cs[tid] = cvload;   // compiler waits only the cbuf load here

  // A (and cbuf) landed; B0/B1 (16 loads) may stay in flight.
  asm volatile("s_waitcnt vmcnt(16) lgkmcnt(0)" ::: "memory");
  __builtin_amdgcn_s_barrier();
  __builtin_amdgcn_sched_barrier(0);

  // ---- A-fragments into registers, kept for all 8 col-tiles ----
  i32x8 afr[2][4];
#pragma unroll
  for (int mi = 0; mi < 2; ++mi) {
    const int r = wr * 64 + mi * 32 + lane31, m = r & 15;
#pragma unroll
    for (int s = 0; s < 4; ++s) {
      const int g0 = s * 4 + half * 2;
      const i32x4 lo = *(const i32x4*)&As[r * D + ((g0 ^ m) * 16)];
      const i32x4 hi = *(const i32x4*)&As[r * D + (((g0 + 1) ^ m) * 16)];
      afr[mi][s] = (i32x8){lo[0], lo[1], lo[2], lo[3], hi[0], hi[1], hi[2], hi[3]};
    }
  }
  // per-lane diag terms (row fixed per (mi,reg,half)); broadcast LDS reads
  float cv2[2][16];
#pragma unroll
  for (int mi = 0; mi < 2; ++mi)
#pragma unroll
    for (int reg = 0; reg < 16; ++reg)
      cv2[mi][reg] = cs[wr * 64 + mi * 32 + (reg & 3) + 8 * (reg >> 2) + 4 * half];

  float sums[2][16];
#pragma unroll
  for (int mi = 0; mi < 2; ++mi)
#pragma unroll
    for (int reg = 0; reg < 16; ++reg) sums[mi][reg] = 0.0f;

  const float K2 = INV_T * LOG2E;

  // ---- main loop over 8 col-tiles ----
#pragma unroll
  for (int t = 0; t < CPG; ++t) {
    if (t < CPG - 1) asm volatile("s_waitcnt vmcnt(8)" ::: "memory");  // B_t landed
    else             asm volatile("s_waitcnt vmcnt(0)" ::: "memory");
    __builtin_amdgcn_s_barrier();
    __builtin_amdgcn_sched_barrier(0);

    const uint8_t* bs = Bs[t & 1];
    f32x16 acc[2][2];
#pragma unroll
    for (int mi = 0; mi < 2; ++mi)
#pragma unroll
      for (int ni = 0; ni < 2; ++ni)
#pragma unroll
        for (int r = 0; r < 16; ++r) acc[mi][ni][r] = 0.0f;

#pragma unroll
    for (int s = 0; s < 4; ++s) {
      const int g0 = s * 4 + half * 2;
      i32x8 b[2];
#pragma unroll
      for (int ni = 0; ni < 2; ++ni) {
        const int r = wc * 64 + ni * 32 + lane31, m = r & 15;
        const i32x4 lo = *(const i32x4*)&bs[r * D + ((g0 ^ m) * 16)];
        const i32x4 hi = *(const i32x4*)&bs[r * D + (((g0 + 1) ^ m) * 16)];
        b[ni] = (i32x8){lo[0], lo[1], lo[2], lo[3], hi[0], hi[1], hi[2], hi[3]};
      }
#pragma unroll
      for (int mi = 0; mi < 2; ++mi)
#pragma unroll
        for (int ni = 0; ni < 2; ++ni)
          acc[mi][ni] = __builtin_amdgcn_mfma_scale_f32_32x32x64_f8f6f4(
              afr[mi][s], b[ni], acc[mi][ni],
              0 /*A fmt fp8*/, 0 /*B fmt fp8*/,
              0, 0x7F7F7F7F /*scaleA=1*/, 0, 0x7F7F7F7F /*scaleB=1*/);
    }

    __builtin_amdgcn_s_barrier();            // all waves done reading Bs[t&1]
    __builtin_amdgcn_sched_barrier(0);

    if (t + 2 < CPG) {                       // refill the buffer just vacated
      const int colTile = (cg * CPG + t + 2) * BN;
#pragma unroll
      for (int i = 0; i < 8; ++i) {
        const int c = i * 256 + tid, r = c >> 4, sl = c & 15;
        const int gg = sl ^ (r & 15);
        __builtin_amdgcn_global_load_lds(
            (gbl_u32*)(B + (size_t)(colTile + r) * D + gg * 16),
            (lds_u32*)&Bs[t & 1][c * 16], 16, 0, 0);
      }
    }

    // exp-accumulate (VALU) overlaps the staging just issued.
    // 32x32 C/D: col=lane&31, row=(reg&3)+8*(reg>>2)+4*(lane>>5) (m74/m101).
#pragma unroll
    for (int mi = 0; mi < 2; ++mi)
#pragma unroll
      for (int reg = 0; reg < 16; ++reg)
        sums[mi][reg] += exp2f(acc[mi][0][reg] * K2 - cv2[mi][reg]) +
                         exp2f(acc[mi][1][reg] * K2 - cv2[mi][reg]);
  }

  // ---- once per block: 32-lane butterfly, then combine the two wc halves ----
#pragma unroll
  for (int mi = 0; mi < 2; ++mi)
#pragma unroll
    for (int reg = 0; reg < 16; ++reg) {
      float v = sums[mi][reg];
      v += __shfl_xor(v, 1);
      v += __shfl_xor(v, 2);
      v += __shfl_xor(v, 4);
      v += __shfl_xor(v, 8);
      v += __shfl_xor(v, 16);
      if (lane31 == 0)
        sm[wr * 64 + mi * 32 + (reg & 3) + 8 * (reg >> 2) + 4 * half][wc] = v;
    }
  __syncthreads();
  if (tid < BM)
    part[((size_t)(z * NCG + cg)) * N + rowTile + tid] = sm[tid][0] + sm[tid][1];
}

// Kernel 3: per-row sum of 8 partials -> log/log1p -> 64 block partials.
__global__ __launch_bounds__(256) void reduce1_kernel(const float* __restrict__ part,
                                                      float* __restrict__ partials) {
  const int bid = blockIdx.x;              // 64 blocks
  const int z = bid >> 5;
  const int row = (bid & 31) * 256 + threadIdx.x;
  float s = 0.0f;
#pragma unroll
  for (int x = 0; x < NCG; ++x)
    s += part[((size_t)(z * NCG + x)) * N + row];
  float val = z ? logf(s) : log1pf(s);
#pragma unroll
  for (int m = 1; m < 64; m <<= 1) val += __shfl_xor(val, m);
  __shared__ float sm[4];
  if ((threadIdx.x & 63) == 0) sm[threadIdx.x >> 6] = val;
  __syncthreads();
  if (threadIdx.x == 0) partials[bid] = sm[0] + sm[1] + sm[2] + sm[3];
}

// Kernel 4: final 64-way sum -> mean loss.
__global__ __launch_bounds__(64) void reduce2_kernel(const float* __restrict__ partials,
                                                     float* __restrict__ out) {
  float v = partials[threadIdx.x];
#pragma unroll
  for (int m = 1; m < 64; m <<= 1) v += __shfl_xor(v, m);
  if (threadIdx.x == 0) out[0] = v * (1.0f / (float)N);
}

extern "C" void kernel_launch(void* const* d_in, const int* in_sizes, int n_in,
                              void* d_out, int out_size, void* d_ws, size_t ws_size,
                              hipStream_t stream) {
  const float* e = (const float*)d_in[0];
  const float* p = (const float*)d_in[1];
  const float* n = (const float*)d_in[2];

  char* w = (char*)d_ws;
  uint8_t* eb = (uint8_t*)w;                                     // 2 MB
  uint8_t* pb = eb + (size_t)N * D;                              // 2 MB
  uint8_t* nb = pb + (size_t)N * D;                              // 2 MB
  float* cbuf = (float*)(nb + (size_t)N * D);                    // 32 KB
  float* part = cbuf + N;                                        // 512 KB
  float* partials = part + (size_t)2 * NCG * N;                  // 256 B

  normalize_kernel<<<N / 4, 256, 0, stream>>>(e, p, n, (uint32_t*)eb, (uint32_t*)pb,
                                              (uint32_t*)nb, cbuf);
  simexp_kernel<<<dim3(NCG, N / BM, 2), 256, 0, stream>>>(eb, pb, nb, cbuf, part);
  reduce1_kernel<<<64, 256, 0, stream>>>(part, partials);
  reduce2_kernel<<<1, 64, 0, stream>>>(partials, (float*)d_out);
}

// Round 3
// 152.099 us; speedup vs baseline: 2.9375x; 2.9375x over previous
//
#include <hip/hip_runtime.h>
#include <stdint.h>

#define N 8192
#define D 256          // elements per row == bytes per fp8 row
#define INV_T 20.0f
#define LOG2E 1.44269504088896340736f
#define BM 128
#define BN 128
#define BK 64
#define NXB 64         // col-blocks (N/BN)

typedef __attribute__((ext_vector_type(16))) float f32x16;
typedef __attribute__((ext_vector_type(4))) int i32x4;
typedef __attribute__((ext_vector_type(8))) int i32x8;

typedef __attribute__((address_space(3))) uint32_t lds_u32;
typedef __attribute__((address_space(1))) const uint32_t gbl_u32;

// Kernel 1: per-row fp32 normalize -> fp8 e4m3 copies (HW cvt, OCP on gfx950);
// c[i] = (e_i . p_i)/T * log2(e) exact fp32 (prefolded for the exp2 epilogue).
__global__ __launch_bounds__(256) void normalize_kernel(
    const float* __restrict__ e, const float* __restrict__ p, const float* __restrict__ n,
    uint32_t* __restrict__ eb, uint32_t* __restrict__ pb, uint32_t* __restrict__ nb,
    float* __restrict__ cbuf) {
  const int tid = threadIdx.x;
  const int wave = tid >> 6, lane = tid & 63;
  const int row = blockIdx.x * 4 + wave;          // one wave per row

  const float4 ev = ((const float4*)(e + (size_t)row * D))[lane];
  const float4 pv = ((const float4*)(p + (size_t)row * D))[lane];
  const float4 nv = ((const float4*)(n + (size_t)row * D))[lane];

  float sse = ev.x*ev.x + ev.y*ev.y + ev.z*ev.z + ev.w*ev.w;
  float ssp = pv.x*pv.x + pv.y*pv.y + pv.z*pv.z + pv.w*pv.w;
  float ssn = nv.x*nv.x + nv.y*nv.y + nv.z*nv.z + nv.w*nv.w;
  float dep = ev.x*pv.x + ev.y*pv.y + ev.z*pv.z + ev.w*pv.w;
#pragma unroll
  for (int m = 1; m < 64; m <<= 1) {
    sse += __shfl_xor(sse, m);
    ssp += __shfl_xor(ssp, m);
    ssn += __shfl_xor(ssn, m);
    dep += __shfl_xor(dep, m);
  }
  const float se = 1.0f / fmaxf(sqrtf(sse), 1e-8f);
  const float sp = 1.0f / fmaxf(sqrtf(ssp), 1e-8f);
  const float sn = 1.0f / fmaxf(sqrtf(ssn), 1e-8f);

  int ue = __builtin_amdgcn_cvt_pk_fp8_f32(ev.x*se, ev.y*se, 0, false);
  ue     = __builtin_amdgcn_cvt_pk_fp8_f32(ev.z*se, ev.w*se, ue, true);
  int up = __builtin_amdgcn_cvt_pk_fp8_f32(pv.x*sp, pv.y*sp, 0, false);
  up     = __builtin_amdgcn_cvt_pk_fp8_f32(pv.z*sp, pv.w*sp, up, true);
  int un = __builtin_amdgcn_cvt_pk_fp8_f32(nv.x*sn, nv.y*sn, 0, false);
  un     = __builtin_amdgcn_cvt_pk_fp8_f32(nv.z*sn, nv.w*sn, un, true);
  eb[row * 64 + lane] = (uint32_t)ue;             // 64 uints = 256 fp8 bytes per row
  pb[row * 64 + lane] = (uint32_t)up;
  nb[row * 64 + lane] = (uint32_t)un;

  if (lane == 0) cbuf[row] = dep * se * sp * INV_T;
}

// Kernel 2: 128x128-tile fp8 GEMM (X @ Y^T) with fused exp row-sums.
// Round-0 skeleton (4 waves x 32 rows x 128 cols) + two verified upgrades:
//  - MX-scaled MFMA 32x32x64_f8f6f4 (fmt 0 = e4m3, unit scales 0x7F = 2^0):
//    bit-exact vs the non-scaled fp8 op (rounds 1-2, absmax 0) at 2x rate.
//  - T3 minimum 2-phase pipeline: double-buffered LDS tiles; per K-step
//    { STAGE(next buf) ; compute(cur buf) ; __syncthreads() }. The trailing
//    __syncthreads emits vmcnt(0)+lgkmcnt(0)+s_barrier, so the stage issued at
//    the top drains while its latency was hidden under this step's ds_read+MFMA.
//    One barrier per K-step (round 0 had two, with a dead drain between them).
// LDS swizzle (round 0, transparent): 16B-group gg of row r stored at slot
// gg ^ ((r>>1)&3); the read XORs again -> canonical K-order (involution).
// Register budget: acc 64 + a 8 + b 8 (ni-serial) + addr ~ 120-140 VGPR.
// __launch_bounds__(256,3): cap ~168 VGPR, 3 blocks/CU (LDS 33.3 KB each).
__global__ __launch_bounds__(256, 3) void simexp_kernel(
    const uint8_t* __restrict__ eb, const uint8_t* __restrict__ pb,
    const uint8_t* __restrict__ nb, const float* __restrict__ cbuf,
    float* __restrict__ part) {
  __shared__ uint8_t As[2][BM * BK];   // 16 KB
  __shared__ uint8_t Bs[2][BN * BK];   // 16 KB
  __shared__ float cs[BM];             // 512 B

  const int z = blockIdx.z;
  const uint8_t* __restrict__ A = z ? pb : eb;
  const uint8_t* __restrict__ B = z ? eb : nb;

  const int tid = threadIdx.x;
  const int wave = tid >> 6, lane = tid & 63;
  const int lane31 = lane & 31, half = lane >> 5;
  const int rowTile = blockIdx.x * BM, colblk = blockIdx.y;
  const int colTile = colblk * BN;
  const int rl = wave * 32 + lane31;              // this lane's A row (local)

  // staging chunk indices (2 x 16B per matrix per thread per K-step)
  const int c0 = tid, c1 = 256 + tid;
  const int r0 = c0 >> 2, g0s = (c0 & 3) ^ ((r0 >> 1) & 3);
  const int r1 = c1 >> 2, g1s = (c1 & 3) ^ ((r1 >> 1) & 3);

#define STAGE(buf, k0)                                                          \
  do {                                                                          \
    __builtin_amdgcn_global_load_lds(                                           \
        (gbl_u32*)(A + (size_t)(rowTile + r0) * D + (k0) + g0s * 16),           \
        (lds_u32*)&As[buf][c0 * 16], 16, 0, 0);                                 \
    __builtin_amdgcn_global_load_lds(                                           \
        (gbl_u32*)(A + (size_t)(rowTile + r1) * D + (k0) + g1s * 16),           \
        (lds_u32*)&As[buf][c1 * 16], 16, 0, 0);                                 \
    __builtin_amdgcn_global_load_lds(                                           \
        (gbl_u32*)(B + (size_t)(colTile + r0) * D + (k0) + g0s * 16),           \
        (lds_u32*)&Bs[buf][c0 * 16], 16, 0, 0);                                 \
    __builtin_amdgcn_global_load_lds(                                           \
        (gbl_u32*)(B + (size_t)(colTile + r1) * D + (k0) + g1s * 16),           \
        (lds_u32*)&Bs[buf][c1 * 16], 16, 0, 0);                                 \
  } while (0)

  if (tid < BM) cs[tid] = cbuf[rowTile + tid] * LOG2E;
  STAGE(0, 0);

  f32x16 acc[4];
#pragma unroll
  for (int ni = 0; ni < 4; ++ni)
#pragma unroll
    for (int r = 0; r < 16; ++r) acc[ni][r] = 0.0f;

  __syncthreads();   // prologue drain: tile 0 + cs visible

  const int ma = (rl >> 1) & 3;          // A-row swizzle key
  const int ga = half * 2;               // this lane's logical 16B-group pair

#pragma unroll
  for (int t = 0; t < 4; ++t) {
    if (t < 3) STAGE((t + 1) & 1, (t + 1) * BK);   // issue next tile FIRST

    const uint8_t* __restrict__ as = As[t & 1];
    const uint8_t* __restrict__ bs = Bs[t & 1];

    const i32x4 alo = *(const i32x4*)&as[rl * BK + (((ga + 0) ^ ma) * 16)];
    const i32x4 ahi = *(const i32x4*)&as[rl * BK + (((ga + 1) ^ ma) * 16)];
    const i32x8 a = (i32x8){alo[0], alo[1], alo[2], alo[3],
                            ahi[0], ahi[1], ahi[2], ahi[3]};
#pragma unroll
    for (int ni = 0; ni < 4; ++ni) {
      const int cl = ni * 32 + lane31, mb = (cl >> 1) & 3;
      const i32x4 blo = *(const i32x4*)&bs[cl * BK + (((ga + 0) ^ mb) * 16)];
      const i32x4 bhi = *(const i32x4*)&bs[cl * BK + (((ga + 1) ^ mb) * 16)];
      const i32x8 b = (i32x8){blo[0], blo[1], blo[2], blo[3],
                              bhi[0], bhi[1], bhi[2], bhi[3]};
      acc[ni] = __builtin_amdgcn_mfma_scale_f32_32x32x64_f8f6f4(
          a, b, acc[ni],
          0 /*A fmt fp8*/, 0 /*B fmt fp8*/,
          0, 0x7F7F7F7F /*scaleA=1*/, 0, 0x7F7F7F7F /*scaleB=1*/);
    }

    __syncthreads();   // drains this step's STAGE (vmcnt 0) + guards buf reuse
  }
#undef STAGE

  // Epilogue. 32x32 C/D: col=lane&31, row=(reg&3)+8*(reg>>2)+4*(lane>>5) (m74/m101).
  const float K2 = INV_T * LOG2E;
#pragma unroll
  for (int reg = 0; reg < 16; ++reg) {
    const int rlocal = (reg & 3) + 8 * (reg >> 2) + 4 * half;
    const int rowl = wave * 32 + rlocal;
    const float cv = cs[rowl];
    float v = 0.0f;
#pragma unroll
    for (int ni = 0; ni < 4; ++ni)
      v += exp2f(acc[ni][reg] * K2 - cv);
    v += __shfl_xor(v, 1);
    v += __shfl_xor(v, 2);
    v += __shfl_xor(v, 4);
    v += __shfl_xor(v, 8);
    v += __shfl_xor(v, 16);
    if (lane31 == 0)
      part[((size_t)(z * NXB + colblk)) * N + rowTile + rowl] = v;
  }
}

// Kernel 3: per-row sum of 64 partials -> log/log1p -> 64 block partials.
__global__ __launch_bounds__(256) void reduce1_kernel(const float* __restrict__ part,
                                                      float* __restrict__ partials) {
  const int bid = blockIdx.x;              // 64 blocks
  const int z = bid >> 5;
  const int row = (bid & 31) * 256 + threadIdx.x;
  float s = 0.0f;
#pragma unroll 8
  for (int x = 0; x < NXB; ++x)
    s += part[((size_t)(z * NXB + x)) * N + row];
  float val = z ? logf(s) : log1pf(s);
#pragma unroll
  for (int m = 1; m < 64; m <<= 1) val += __shfl_xor(val, m);
  __shared__ float sm[4];
  if ((threadIdx.x & 63) == 0) sm[threadIdx.x >> 6] = val;
  __syncthreads();
  if (threadIdx.x == 0) partials[bid] = sm[0] + sm[1] + sm[2] + sm[3];
}

// Kernel 4: final 64-way sum -> mean loss.
__global__ __launch_bounds__(64) void reduce2_kernel(const float* __restrict__ partials,
                                                     float* __restrict__ out) {
  float v = partials[threadIdx.x];
#pragma unroll
  for (int m = 1; m < 64; m <<= 1) v += __shfl_xor(v, m);
  if (threadIdx.x == 0) out[0] = v * (1.0f / (float)N);
}

extern "C" void kernel_launch(void* const* d_in, const int* in_sizes, int n_in,
                              void* d_out, int out_size, void* d_ws, size_t ws_size,
                              hipStream_t stream) {
  const float* e = (const float*)d_in[0];
  const float* p = (const float*)d_in[1];
  const float* n = (const float*)d_in[2];

  char* w = (char*)d_ws;
  uint8_t* eb = (uint8_t*)w;                                     // 2 MB
  uint8_t* pb = eb + (size_t)N * D;                              // 2 MB
  uint8_t* nb = pb + (size_t)N * D;                              // 2 MB
  float* cbuf = (float*)(nb + (size_t)N * D);                    // 32 KB
  float* part = cbuf + N;                                        // 4 MB
  float* partials = part + (size_t)2 * NXB * N;                  // 256 B

  normalize_kernel<<<N / 4, 256, 0, stream>>>(e, p, n, (uint32_t*)eb, (uint32_t*)pb,
                                              (uint32_t*)nb, cbuf);
  simexp_kernel<<<dim3(N / BM, N / BN, 2), 256, 0, stream>>>(eb, pb, nb, cbuf, part);
  reduce1_kernel<<<64, 256, 0, stream>>>(part, partials);
  reduce2_kernel<<<1, 64, 0, stream>>>(partials, (float*)d_out);
}

// Round 4
// 135.853 us; speedup vs baseline: 3.2888x; 1.1196x over previous
//
#include <hip/hip_runtime.h>
#include <stdint.h>

#define N 8192
#define D 256          // elements per row == bytes per fp8 row
#define INV_T 20.0f
#define LOG2E 1.44269504088896340736f
#define BM 128
#define BN 128
#define NXB 64         // col-blocks (N/BN)

typedef __attribute__((ext_vector_type(16))) float f32x16;
typedef __attribute__((ext_vector_type(4))) int i32x4;
typedef __attribute__((ext_vector_type(8))) int i32x8;

typedef __attribute__((address_space(3))) uint32_t lds_u32;
typedef __attribute__((address_space(1))) const uint32_t gbl_u32;

// DPP-fused butterfly add levels (VALU, replaces ds_swizzle+add):
//   xor1 = quad_perm [1,0,3,2] (0xB1), xor2 = quad_perm [2,3,0,1] (0x4E);
//   after those, quads are uniform, so row_half_mirror (0x141) == xor4 and
//   row_mirror (0x140) == xor8. Same pairwise tree as __shfl_xor -> bit-identical.
#define DPP_ADD(v, ctrl)                                                      \
  ((v) + __builtin_bit_cast(float, __builtin_amdgcn_update_dpp(               \
             0, __builtin_bit_cast(int, (v)), (ctrl), 0xf, 0xf, true)))

// Kernel 1: per-row fp32 normalize -> fp8 e4m3 copies (HW cvt, OCP on gfx950);
// c[i] = (e_i . p_i)/T exact fp32.
__global__ __launch_bounds__(256) void normalize_kernel(
    const float* __restrict__ e, const float* __restrict__ p, const float* __restrict__ n,
    uint32_t* __restrict__ eb, uint32_t* __restrict__ pb, uint32_t* __restrict__ nb,
    float* __restrict__ cbuf) {
  const int tid = threadIdx.x;
  const int wave = tid >> 6, lane = tid & 63;
  const int row = blockIdx.x * 4 + wave;          // one wave per row

  const float4 ev = ((const float4*)(e + (size_t)row * D))[lane];
  const float4 pv = ((const float4*)(p + (size_t)row * D))[lane];
  const float4 nv = ((const float4*)(n + (size_t)row * D))[lane];

  float sse = ev.x*ev.x + ev.y*ev.y + ev.z*ev.z + ev.w*ev.w;
  float ssp = pv.x*pv.x + pv.y*pv.y + pv.z*pv.z + pv.w*pv.w;
  float ssn = nv.x*nv.x + nv.y*nv.y + nv.z*nv.z + nv.w*nv.w;
  float dep = ev.x*pv.x + ev.y*pv.y + ev.z*pv.z + ev.w*pv.w;
#pragma unroll
  for (int m = 1; m < 64; m <<= 1) {
    sse += __shfl_xor(sse, m);
    ssp += __shfl_xor(ssp, m);
    ssn += __shfl_xor(ssn, m);
    dep += __shfl_xor(dep, m);
  }
  const float se = 1.0f / fmaxf(sqrtf(sse), 1e-8f);
  const float sp = 1.0f / fmaxf(sqrtf(ssp), 1e-8f);
  const float sn = 1.0f / fmaxf(sqrtf(ssn), 1e-8f);

  int ue = __builtin_amdgcn_cvt_pk_fp8_f32(ev.x*se, ev.y*se, 0, false);
  ue     = __builtin_amdgcn_cvt_pk_fp8_f32(ev.z*se, ev.w*se, ue, true);
  int up = __builtin_amdgcn_cvt_pk_fp8_f32(pv.x*sp, pv.y*sp, 0, false);
  up     = __builtin_amdgcn_cvt_pk_fp8_f32(pv.z*sp, pv.w*sp, up, true);
  int un = __builtin_amdgcn_cvt_pk_fp8_f32(nv.x*sn, nv.y*sn, 0, false);
  un     = __builtin_amdgcn_cvt_pk_fp8_f32(nv.z*sn, nv.w*sn, un, true);
  eb[row * 64 + lane] = (uint32_t)ue;             // 64 uints = 256 fp8 bytes per row
  pb[row * 64 + lane] = (uint32_t)up;
  nb[row * 64 + lane] = (uint32_t)un;

  if (lane == 0) cbuf[row] = dep * se * sp * INV_T;
}

// Kernel 2: 128x128-tile fp8 GEMM (X @ Y^T) with fused exp row-sums.
// Structure (round 4): ONE barrier per block, no K-loop barriers.
//  - B staged full-K (32 KB, single buffer) via global_load_lds with the
//    round-1 verified 16-slot XOR layout: group gg of row r at slot gg^(r&15)
//    -> measured 0 bank conflicts on the b128 reads; read XORs again
//    (involution) so K-order is canonical.
//  - A never touches LDS: each lane direct-loads its row's K-slices into
//    32 VGPRs (8 x dwordx4, L1/L2-served; block A footprint 32 KB = L1-sized).
//  - MX-scaled MFMA 32x32x64_f8f6f4 (fmt 0 = e4m3, unit scales): bit-exact vs
//    non-scaled fp8 (rounds 1-3, absmax 0) at 2x rate.
//  - Epilogue reduce: DPP butterfly (4 VALU dpp-adds) + 1 ds_swizzle xor16 +
//    1 add; DS ops 80 -> 16 per thread, identical add tree.
// Regs: ~100 arch + 64 acc(AGPR) -> launch_bounds(256,3) cap 170, no spill.
// LDS 32.5 KB; 3 blocks/CU, waves drift freely (no syncs) -> pipes stay mixed.
__global__ __launch_bounds__(256, 3) void simexp_kernel(
    const uint8_t* __restrict__ eb, const uint8_t* __restrict__ pb,
    const uint8_t* __restrict__ nb, const float* __restrict__ cbuf,
    float* __restrict__ part) {
  __shared__ uint8_t Bs[BN * D];    // 32 KB, full-K B tile (swizzled)
  __shared__ float cs[BM];          // 512 B

  const int z = blockIdx.z;
  const uint8_t* __restrict__ A = z ? pb : eb;
  const uint8_t* __restrict__ B = z ? eb : nb;

  const int tid = threadIdx.x;
  const int wave = tid >> 6, lane = tid & 63;
  const int lane31 = lane & 31, half = lane >> 5;
  const int rowTile = blockIdx.x * BM, colblk = blockIdx.y;
  const int colTile = colblk * BN;

  // ---- stage B (full K): 2048 16B chunks, 8 per thread, coalesced ----
#pragma unroll
  for (int i = 0; i < 8; ++i) {
    const int c = i * 256 + tid, r = c >> 4, sl = c & 15;
    const int gg = sl ^ (r & 15);               // swizzled SOURCE group
    __builtin_amdgcn_global_load_lds(
        (gbl_u32*)(B + (size_t)(colTile + r) * D + gg * 16),
        (lds_u32*)&Bs[c * 16], 16, 0, 0);
  }

  // ---- A direct to registers: this lane's row, its K-half, all 4 K-steps ----
  const int arow = rowTile + wave * 32 + lane31;
  const uint8_t* __restrict__ Arow = A + (size_t)arow * D + half * 32;
  i32x8 afr[4];
#pragma unroll
  for (int s = 0; s < 4; ++s) {
    const i32x4 lo = *(const i32x4*)(Arow + s * 64);
    const i32x4 hi = *(const i32x4*)(Arow + s * 64 + 16);
    afr[s] = (i32x8){lo[0], lo[1], lo[2], lo[3], hi[0], hi[1], hi[2], hi[3]};
  }

  if (tid < BM) cs[tid] = cbuf[rowTile + tid] * LOG2E;

  f32x16 acc[4];
#pragma unroll
  for (int ni = 0; ni < 4; ++ni)
#pragma unroll
    for (int r = 0; r < 16; ++r) acc[ni][r] = 0.0f;

  __syncthreads();   // the ONLY barrier: B tile + cs visible, A regs loaded

  // ---- K loop: 4 steps of K=64, zero barriers, compiler free to pipeline ----
#pragma unroll
  for (int s = 0; s < 4; ++s) {
    const int g0 = s * 4 + half * 2;            // this lane's two logical groups
#pragma unroll
    for (int ni = 0; ni < 4; ++ni) {
      const int cl = ni * 32 + lane31, m = cl & 15;
      const i32x4 blo = *(const i32x4*)&Bs[cl * D + ((g0 ^ m) * 16)];
      const i32x4 bhi = *(const i32x4*)&Bs[cl * D + (((g0 + 1) ^ m) * 16)];
      const i32x8 b = (i32x8){blo[0], blo[1], blo[2], blo[3],
                              bhi[0], bhi[1], bhi[2], bhi[3]};
      acc[ni] = __builtin_amdgcn_mfma_scale_f32_32x32x64_f8f6f4(
          afr[s], b, acc[ni],
          0 /*A fmt fp8*/, 0 /*B fmt fp8*/,
          0, 0x7F7F7F7F /*scaleA=1*/, 0, 0x7F7F7F7F /*scaleB=1*/);
    }
  }

  // ---- epilogue: exp2 + row-sum over this wave's 128 cols ----
  // 32x32 C/D: col=lane&31, row=(reg&3)+8*(reg>>2)+4*(lane>>5) (m74/m101).
  const float K2 = INV_T * LOG2E;
#pragma unroll
  for (int reg = 0; reg < 16; ++reg) {
    const int rlocal = (reg & 3) + 8 * (reg >> 2) + 4 * half;
    const int rowl = wave * 32 + rlocal;
    const float cv = cs[rowl];
    float v = exp2f(acc[0][reg] * K2 - cv) + exp2f(acc[1][reg] * K2 - cv) +
              exp2f(acc[2][reg] * K2 - cv) + exp2f(acc[3][reg] * K2 - cv);
    v = DPP_ADD(v, 0xB1);    // xor1: quad_perm [1,0,3,2]
    v = DPP_ADD(v, 0x4E);    // xor2: quad_perm [2,3,0,1]
    v = DPP_ADD(v, 0x141);   // xor4: row_half_mirror
    v = DPP_ADD(v, 0x140);   // xor8: row_mirror
    v += __builtin_bit_cast(float, __builtin_amdgcn_ds_swizzle(
             __builtin_bit_cast(int, v), 0x401F));  // xor16
    if (lane31 == 0)
      part[((size_t)(z * NXB + colblk)) * N + rowTile + rowl] = v;
  }
}

// Kernel 3: per-row sum of 64 partials -> log/log1p -> 64 block partials.
__global__ __launch_bounds__(256) void reduce1_kernel(const float* __restrict__ part,
                                                      float* __restrict__ partials) {
  const int bid = blockIdx.x;              // 64 blocks
  const int z = bid >> 5;
  const int row = (bid & 31) * 256 + threadIdx.x;
  float s = 0.0f;
#pragma unroll 8
  for (int x = 0; x < NXB; ++x)
    s += part[((size_t)(z * NXB + x)) * N + row];
  float val = z ? logf(s) : log1pf(s);
#pragma unroll
  for (int m = 1; m < 64; m <<= 1) val += __shfl_xor(val, m);
  __shared__ float sm[4];
  if ((threadIdx.x & 63) == 0) sm[threadIdx.x >> 6] = val;
  __syncthreads();
  if (threadIdx.x == 0) partials[bid] = sm[0] + sm[1] + sm[2] + sm[3];
}

// Kernel 4: final 64-way sum -> mean loss.
__global__ __launch_bounds__(64) void reduce2_kernel(const float* __restrict__ partials,
                                                     float* __restrict__ out) {
  float v = partials[threadIdx.x];
#pragma unroll
  for (int m = 1; m < 64; m <<= 1) v += __shfl_xor(v, m);
  if (threadIdx.x == 0) out[0] = v * (1.0f / (float)N);
}

extern "C" void kernel_launch(void* const* d_in, const int* in_sizes, int n_in,
                              void* d_out, int out_size, void* d_ws, size_t ws_size,
                              hipStream_t stream) {
  const float* e = (const float*)d_in[0];
  const float* p = (const float*)d_in[1];
  const float* n = (const float*)d_in[2];

  char* w = (char*)d_ws;
  uint8_t* eb = (uint8_t*)w;                                     // 2 MB
  uint8_t* pb = eb + (size_t)N * D;                              // 2 MB
  uint8_t* nb = pb + (size_t)N * D;                              // 2 MB
  float* cbuf = (float*)(nb + (size_t)N * D);                    // 32 KB
  float* part = cbuf + N;                                        // 4 MB
  float* partials = part + (size_t)2 * NXB * N;                  // 256 B

  normalize_kernel<<<N / 4, 256, 0, stream>>>(e, p, n, (uint32_t*)eb, (uint32_t*)pb,
                                              (uint32_t*)nb, cbuf);
  simexp_kernel<<<dim3(N / BM, N / BN, 2), 256, 0, stream>>>(eb, pb, nb, cbuf, part);
  reduce1_kernel<<<64, 256, 0, stream>>>(part, partials);
  reduce2_kernel<<<1, 64, 0, stream>>>(partials, (float*)d_out);
}

// Round 5
// 127.524 us; speedup vs baseline: 3.5036x; 1.0653x over previous
//
#include <hip/hip_runtime.h>
#include <stdint.h>

#define N 8192
#define D 256          // elements per row == bytes per fp8 row
#define INV_T 20.0f
#define LOG2E 1.44269504088896340736f
#define BM 128
#define BN 128
#define NXB 64         // col-blocks (N/BN)

typedef __attribute__((ext_vector_type(16))) float f32x16;
typedef __attribute__((ext_vector_type(4))) int i32x4;
typedef __attribute__((ext_vector_type(8))) int i32x8;

typedef __attribute__((address_space(3))) uint32_t lds_u32;
typedef __attribute__((address_space(1))) const uint32_t gbl_u32;

// Raw v_exp_f32 (2^x). Library exp2f carries a multi-instruction guard for
// |x|>~126; our args are bounded (|x| <= ~62), so the raw trans op is safe.
static __device__ __forceinline__ float fast_exp2(float x) {
#if __has_builtin(__builtin_amdgcn_exp2f)
  return __builtin_amdgcn_exp2f(x);
#else
  float r;
  asm("v_exp_f32 %0, %1" : "=v"(r) : "v"(x));
  return r;
#endif
}

// DPP-fused butterfly add levels (VALU, replaces ds_swizzle+add):
//   xor1 = quad_perm [1,0,3,2] (0xB1), xor2 = quad_perm [2,3,0,1] (0x4E);
//   after those, quads are uniform, so row_half_mirror (0x141) == xor4 and
//   row_mirror (0x140) == xor8. Same pairwise tree as __shfl_xor -> bit-identical.
#define DPP_ADD(v, ctrl)                                                      \
  ((v) + __builtin_bit_cast(float, __builtin_amdgcn_update_dpp(               \
             0, __builtin_bit_cast(int, (v)), (ctrl), 0xf, 0xf, true)))

// Kernel 1: per-row fp32 normalize -> fp8 e4m3 copies (HW cvt, OCP on gfx950);
// c[i] = (e_i . p_i)/T exact fp32.
__global__ __launch_bounds__(256) void normalize_kernel(
    const float* __restrict__ e, const float* __restrict__ p, const float* __restrict__ n,
    uint32_t* __restrict__ eb, uint32_t* __restrict__ pb, uint32_t* __restrict__ nb,
    float* __restrict__ cbuf) {
  const int tid = threadIdx.x;
  const int wave = tid >> 6, lane = tid & 63;
  const int row = blockIdx.x * 4 + wave;          // one wave per row

  const float4 ev = ((const float4*)(e + (size_t)row * D))[lane];
  const float4 pv = ((const float4*)(p + (size_t)row * D))[lane];
  const float4 nv = ((const float4*)(n + (size_t)row * D))[lane];

  float sse = ev.x*ev.x + ev.y*ev.y + ev.z*ev.z + ev.w*ev.w;
  float ssp = pv.x*pv.x + pv.y*pv.y + pv.z*pv.z + pv.w*pv.w;
  float ssn = nv.x*nv.x + nv.y*nv.y + nv.z*nv.z + nv.w*nv.w;
  float dep = ev.x*pv.x + ev.y*pv.y + ev.z*pv.z + ev.w*pv.w;
#pragma unroll
  for (int m = 1; m < 64; m <<= 1) {
    sse += __shfl_xor(sse, m);
    ssp += __shfl_xor(ssp, m);
    ssn += __shfl_xor(ssn, m);
    dep += __shfl_xor(dep, m);
  }
  const float se = 1.0f / fmaxf(sqrtf(sse), 1e-8f);
  const float sp = 1.0f / fmaxf(sqrtf(ssp), 1e-8f);
  const float sn = 1.0f / fmaxf(sqrtf(ssn), 1e-8f);

  int ue = __builtin_amdgcn_cvt_pk_fp8_f32(ev.x*se, ev.y*se, 0, false);
  ue     = __builtin_amdgcn_cvt_pk_fp8_f32(ev.z*se, ev.w*se, ue, true);
  int up = __builtin_amdgcn_cvt_pk_fp8_f32(pv.x*sp, pv.y*sp, 0, false);
  up     = __builtin_amdgcn_cvt_pk_fp8_f32(pv.z*sp, pv.w*sp, up, true);
  int un = __builtin_amdgcn_cvt_pk_fp8_f32(nv.x*sn, nv.y*sn, 0, false);
  un     = __builtin_amdgcn_cvt_pk_fp8_f32(nv.z*sn, nv.w*sn, un, true);
  eb[row * 64 + lane] = (uint32_t)ue;             // 64 uints = 256 fp8 bytes per row
  pb[row * 64 + lane] = (uint32_t)up;
  nb[row * 64 + lane] = (uint32_t)un;

  if (lane == 0) cbuf[row] = dep * se * sp * INV_T;
}

// Kernel 2: 128x128-tile fp8 GEMM (X @ Y^T) with fused exp row-sums.
// Round-4 structure (67 us, 0 bank conflicts, no spill) + VALU diet:
//  - B staged full-K (32 KB, single buffer, ONE barrier) via global_load_lds,
//    16-slot XOR layout: group gg of row r at slot gg^(r&15) (read XORs again
//    -> canonical K-order; involution).
//  - A direct to registers (8 x dwordx4 per lane; block footprint 32 KB, L1/L2).
//  - MX-scaled MFMA 32x32x64_f8f6f4 (fmt 0 = e4m3, unit scales): bit-exact vs
//    non-scaled fp8 (rounds 1-4, absmax 0) at 2x rate.
//  - NEW: raw v_exp_f32 for exp2 (args bounded, no OCML guard code): the
//    single largest VALU overhead removed (~64x5 instrs/thread).
//  - NEW: B-read address = bbase[ni] ^ (s<<6) ^ (j<<4): since D=256, the byte
//    address factors into disjoint XOR fields; 1 v_xor per read replaces
//    xor+shl+add. bbase[ni] = (cl<<8) ^ ((cl&15)<<4) ^ (half<<5), per-lane const.
//  - Epilogue reduce: DPP butterfly + 1 ds_swizzle xor16 (round 4).
__global__ __launch_bounds__(256, 3) void simexp_kernel(
    const uint8_t* __restrict__ eb, const uint8_t* __restrict__ pb,
    const uint8_t* __restrict__ nb, const float* __restrict__ cbuf,
    float* __restrict__ part) {
  __shared__ uint8_t Bs[BN * D];    // 32 KB, full-K B tile (swizzled)
  __shared__ float cs[BM];          // 512 B

  const int z = blockIdx.z;
  const uint8_t* __restrict__ A = z ? pb : eb;
  const uint8_t* __restrict__ B = z ? eb : nb;

  const int tid = threadIdx.x;
  const int wave = tid >> 6, lane = tid & 63;
  const int lane31 = lane & 31, half = lane >> 5;
  const int rowTile = blockIdx.x * BM, colblk = blockIdx.y;
  const int colTile = colblk * BN;

  // ---- stage B (full K): 2048 16B chunks, 8 per thread, coalesced ----
#pragma unroll
  for (int i = 0; i < 8; ++i) {
    const int c = i * 256 + tid, r = c >> 4, sl = c & 15;
    const int gg = sl ^ (r & 15);               // swizzled SOURCE group
    __builtin_amdgcn_global_load_lds(
        (gbl_u32*)(B + (size_t)(colTile + r) * D + gg * 16),
        (lds_u32*)&Bs[c * 16], 16, 0, 0);
  }

  // ---- A direct to registers: this lane's row, its K-half, all 4 K-steps ----
  const int arow = rowTile + wave * 32 + lane31;
  const uint8_t* __restrict__ Arow = A + (size_t)arow * D + half * 32;
  i32x8 afr[4];
#pragma unroll
  for (int s = 0; s < 4; ++s) {
    const i32x4 lo = *(const i32x4*)(Arow + s * 64);
    const i32x4 hi = *(const i32x4*)(Arow + s * 64 + 16);
    afr[s] = (i32x8){lo[0], lo[1], lo[2], lo[3], hi[0], hi[1], hi[2], hi[3]};
  }

  if (tid < BM) cs[tid] = cbuf[rowTile + tid] * LOG2E;

  // per-ni XOR-folded B fragment base addresses (byte offsets into Bs)
  int bbase[4];
#pragma unroll
  for (int ni = 0; ni < 4; ++ni) {
    const int cl = ni * 32 + lane31;
    bbase[ni] = (cl << 8) ^ ((cl & 15) << 4) ^ (half << 5);
  }

  f32x16 acc[4];
#pragma unroll
  for (int ni = 0; ni < 4; ++ni)
#pragma unroll
    for (int r = 0; r < 16; ++r) acc[ni][r] = 0.0f;

  __syncthreads();   // the ONLY barrier: B tile + cs visible

  // ---- K loop: 4 steps of K=64, zero barriers, compiler free to pipeline ----
#pragma unroll
  for (int s = 0; s < 4; ++s) {
#pragma unroll
    for (int ni = 0; ni < 4; ++ni) {
      const int alo = bbase[ni] ^ (s << 6);     // 1 v_xor (s<<6 is inline const)
      const i32x4 blo = *(const i32x4*)&Bs[alo];
      const i32x4 bhi = *(const i32x4*)&Bs[alo ^ 16];
      const i32x8 b = (i32x8){blo[0], blo[1], blo[2], blo[3],
                              bhi[0], bhi[1], bhi[2], bhi[3]};
      acc[ni] = __builtin_amdgcn_mfma_scale_f32_32x32x64_f8f6f4(
          afr[s], b, acc[ni],
          0 /*A fmt fp8*/, 0 /*B fmt fp8*/,
          0, 0x7F7F7F7F /*scaleA=1*/, 0, 0x7F7F7F7F /*scaleB=1*/);
    }
  }

  // ---- epilogue: exp2 + row-sum over this wave's 128 cols ----
  // 32x32 C/D: col=lane&31, row=(reg&3)+8*(reg>>2)+4*(lane>>5) (m74/m101).
  const float K2 = INV_T * LOG2E;
#pragma unroll
  for (int reg = 0; reg < 16; ++reg) {
    const int rlocal = (reg & 3) + 8 * (reg >> 2) + 4 * half;
    const int rowl = wave * 32 + rlocal;
    const float cv = cs[rowl];
    float v = fast_exp2(acc[0][reg] * K2 - cv) + fast_exp2(acc[1][reg] * K2 - cv) +
              fast_exp2(acc[2][reg] * K2 - cv) + fast_exp2(acc[3][reg] * K2 - cv);
    v = DPP_ADD(v, 0xB1);    // xor1: quad_perm [1,0,3,2]
    v = DPP_ADD(v, 0x4E);    // xor2: quad_perm [2,3,0,1]
    v = DPP_ADD(v, 0x141);   // xor4: row_half_mirror
    v = DPP_ADD(v, 0x140);   // xor8: row_mirror
    v += __builtin_bit_cast(float, __builtin_amdgcn_ds_swizzle(
             __builtin_bit_cast(int, v), 0x401F));  // xor16
    if (lane31 == 0)
      part[((size_t)(z * NXB + colblk)) * N + rowTile + rowl] = v;
  }
}

// Kernel 3: per-row sum of 64 partials -> log/log1p -> 256 block partials.
// 256 x 64-thread blocks (was 64 x 256): engages all 256 CUs; per-row serial
// sum order unchanged (one thread per row).
__global__ __launch_bounds__(64) void reduce1_kernel(const float* __restrict__ part,
                                                     float* __restrict__ partials) {
  const int bid = blockIdx.x;              // 256 blocks
  const int z = bid >> 7;                  // 128 blocks per z-slice
  const int row = (bid & 127) * 64 + threadIdx.x;
  float s = 0.0f;
#pragma unroll 8
  for (int x = 0; x < NXB; ++x)
    s += part[((size_t)(z * NXB + x)) * N + row];
  float val = z ? logf(s) : log1pf(s);
#pragma unroll
  for (int m = 1; m < 64; m <<= 1) val += __shfl_xor(val, m);
  if (threadIdx.x == 0) partials[bid] = val;
}

// Kernel 4: final 256-way sum -> mean loss.
__global__ __launch_bounds__(256) void reduce2_kernel(const float* __restrict__ partials,
                                                      float* __restrict__ out) {
  const int tid = threadIdx.x;
  float v = partials[tid];
#pragma unroll
  for (int m = 1; m < 64; m <<= 1) v += __shfl_xor(v, m);
  __shared__ float sm[4];
  if ((tid & 63) == 0) sm[tid >> 6] = v;
  __syncthreads();
  if (tid == 0) out[0] = (sm[0] + sm[1] + sm[2] + sm[3]) * (1.0f / (float)N);
}

extern "C" void kernel_launch(void* const* d_in, const int* in_sizes, int n_in,
                              void* d_out, int out_size, void* d_ws, size_t ws_size,
                              hipStream_t stream) {
  const float* e = (const float*)d_in[0];
  const float* p = (const float*)d_in[1];
  const float* n = (const float*)d_in[2];

  char* w = (char*)d_ws;
  uint8_t* eb = (uint8_t*)w;                                     // 2 MB
  uint8_t* pb = eb + (size_t)N * D;                              // 2 MB
  uint8_t* nb = pb + (size_t)N * D;                              // 2 MB
  float* cbuf = (float*)(nb + (size_t)N * D);                    // 32 KB
  float* part = cbuf + N;                                        // 4 MB
  float* partials = part + (size_t)2 * NXB * N;                  // 1 KB

  normalize_kernel<<<N / 4, 256, 0, stream>>>(e, p, n, (uint32_t*)eb, (uint32_t*)pb,
                                              (uint32_t*)nb, cbuf);
  simexp_kernel<<<dim3(N / BM, N / BN, 2), 256, 0, stream>>>(eb, pb, nb, cbuf, part);
  reduce1_kernel<<<256, 64, 0, stream>>>(part, partials);
  reduce2_kernel<<<1, 256, 0, stream>>>(partials, (float*)d_out);
}